// Round 16
// baseline (9321.175 us; speedup 1.0000x reference)
//
#include <hip/hip_runtime.h>

#define T_LEN 1024
#define BATCH 256
#define HID   30

__device__ __forceinline__ float ftanh(float x) {
    x = fminf(fmaxf(x, -15.0f), 15.0f);
    float e = __expf(2.0f * x);
    return (e - 1.0f) / (e + 1.0f);
}

__device__ __forceinline__ float rl(float v, int srclane) {
    return __int_as_float(__builtin_amdgcn_readlane(__float_as_int(v), srclane));
}

// Single-wave LSTM layer: one 64-thread block per (batch, dir).
// Round-15 post-mortem: allocator caps at ~132 VGPR regardless of
// waves_per_eu/pins -> 180 register-resident weights are unattainable.
// Restructure: Whh (60/lane) stays in regs (fits); Wih lives in LDS with a
// conflict-free [k/4][row][4] layout (lane l reads row(l)*16B -> lanes 0..7
// span all 32 banks; structural-minimum ds_read_b128). DS reads overlap VALU
// FMA issue. h via readlane; f/o via shfl; x windows in LDS; zero barriers.
template<int IN_L>
__global__ __launch_bounds__(64)
void lstm_wave(const float* __restrict__ in,
               float* __restrict__ out,
               const float* __restrict__ wih,   // [2,120,IN_L] pre-offset to layer
               const float* __restrict__ whh,   // [2,120,30]
               const float* __restrict__ bias,  // [2,120]
               const float* __restrict__ h0,    // [2,B,30]
               const float* __restrict__ c0)    // [2,B,30]
{
    constexpr int IN_P  = (IN_L + 3) & ~3;   // padded K (24 or 60)
    constexpr int WS    = 8;                 // steps per staged x-window
    constexpr int NW    = T_LEN / WS;
    constexpr int XELE  = WS * IN_L;
    constexpr int NLOAD = (XELE + 63) / 64;
    constexpr int NQ    = IN_P / 4;          // K quads

    const int b = blockIdx.x, d = blockIdx.y, lane = threadIdx.x;

    __shared__ __align__(16) float wlds[120 * IN_P];     // [(k/4)][row][k%4]
    __shared__ __align__(16) float xt[2][WS * IN_P];

    const int rowA = (lane < 60) ? lane : 59;            // lanes 60..63 clamp

    // ---- Whh + bias in registers (2 gate rows per lane) ----
    float whA[HID], whB[HID];
    {
        const float* ha = whh + (size_t)(d * 120 + rowA) * HID;
        const float* hb = ha + 60 * HID;
        #pragma unroll
        for (int k = 0; k < HID; k++) { whA[k] = ha[k]; whB[k] = hb[k]; }
    }
    float bA = bias[d * 120 + rowA];
    float bB = bias[d * 120 + 60 + rowA];

    // ---- Wih -> LDS, swizzled: idx = (k/4)*480 + row*4 + (k%4) ----
    for (int e = lane; e < 120 * IN_P; e += 64) {
        int row = e / IN_P, k = e % IN_P;
        float v = (k < IN_L) ? wih[(size_t)(d * 120 + row) * IN_L + k] : 0.f;
        wlds[(k >> 2) * 480 + row * 4 + (k & 3)] = v;
    }
    // zero x pad columns once (undefined LDS could be Inf/NaN; 0*Inf=NaN)
    if constexpr (IN_P > IN_L) {
        constexpr int NPAD = IN_P - IN_L;
        for (int e = lane; e < 2 * WS * NPAD; e += 64) {
            int buf = e / (WS * NPAD), r = e % (WS * NPAD);
            xt[buf][(r / NPAD) * IN_P + IN_L + (r % NPAD)] = 0.f;
        }
    }

    // ---- initial h (lanes 0..29 hold h_j) and c ----
    float hval = 0.f, cval = 0.f;
    {
        int j = (lane < HID) ? lane : 0;
        float hl = h0[(size_t)(d * BATCH + b) * HID + j];
        float cl = c0[(size_t)(d * BATCH + b) * HID + j];
        if (lane < HID) { hval = hl; cval = cl; }
    }

    const int t0 = d ? (T_LEN - 1) : 0;
    const int ts = d ? -1 : 1;
    const float* xin = in + (size_t)b * T_LEN * IN_L;
    float* outp = out + (size_t)b * T_LEN * 60 + (size_t)t0 * 60 + d * HID
                      + ((lane < HID) ? lane : 0);

    // activation constants: slot B = tanh(g) lanes<30, sigmoid(o) lanes>=30
    const float km  = (lane < HID) ? 2.f : 1.f;
    const float kba = (lane < HID) ? 2.f : 1.f;
    const float kbb = (lane < HID) ? -1.f : 0.f;

    float xg[NLOAD];

    auto stage_load = [&](int w) {
        const float* base = xin + (size_t)(t0 + ts * (WS * w)) * IN_L;
        #pragma unroll
        for (int r = 0; r < NLOAD; r++) {
            int e = r * 64 + lane;
            if (e < XELE) xg[r] = base[ts * (e / IN_L) * IN_L + (e % IN_L)];
        }
    };
    auto stage_write = [&](int buf) {
        // WAR: drain pending LDS reads before overwrite
        asm volatile("s_waitcnt lgkmcnt(0)" ::: "memory");
        #pragma unroll
        for (int r = 0; r < NLOAD; r++) {
            int e = r * 64 + lane;
            if (e < XELE) xt[buf][(e / IN_L) * IN_P + (e % IN_L)] = xg[r];
        }
        // RAW: writes visible before next window's reads
        asm volatile("s_waitcnt lgkmcnt(0)" ::: "memory");
        __builtin_amdgcn_sched_barrier(0);
    };

    stage_load(0);
    stage_write(0);   // trailing fence also covers the wlds/pad writes above

    for (int w = 0; w < NW; ++w) {
        if (w + 1 < NW) stage_load(w + 1);   // prefetch next window
        const float* xb = xt[w & 1];
        #pragma unroll
        for (int s = 0; s < WS; ++s) {
            float aA0 = bA, aA1 = 0.f, aB0 = bB, aB1 = 0.f;
            // ---- Wih part: LDS weights (conflict-free) x LDS x (broadcast) ----
            #pragma unroll
            for (int q = 0; q < NQ; q++) {
                float4 xv = *(const float4*)&xb[s * IN_P + q * 4];
                float4 wa = *(const float4*)&wlds[q * 480 + rowA * 4];
                float4 wb = *(const float4*)&wlds[q * 480 + rowA * 4 + 240];
                aA0 += wa.x * xv.x; aA1 += wa.y * xv.y;
                aA0 += wa.z * xv.z; aA1 += wa.w * xv.w;
                aB0 += wb.x * xv.x; aB1 += wb.y * xv.y;
                aB0 += wb.z * xv.z; aB1 += wb.w * xv.w;
            }
            // ---- Whh part: register weights x readlane-broadcast h ----
            #pragma unroll
            for (int k = 0; k < HID; k += 2) {
                float h0v = rl(hval, k), h1v = rl(hval, k + 1);
                aA0 += whA[k] * h0v;     aB0 += whB[k] * h0v;
                aA1 += whA[k + 1] * h1v; aB1 += whB[k + 1] * h1v;
            }
            float aA = aA0 + aA1, aB = aB0 + aB1;

            // slot A: sigmoid (i lanes<30, f lanes 30..59)
            float sA = __builtin_amdgcn_rcpf(1.f + __expf(-aA));
            // slot B: tanh(g)/sigmoid(o), branch-free
            float sB = __builtin_amdgcn_rcpf(1.f + __expf(-(km * aB)));
            sB = kba * sB + kbb;

            float sf = __shfl(sA, lane + 30, 64);
            float so = __shfl(sB, lane + 30, 64);

            cval = sf * cval + sA * sB;                  // c' = f*c + i*tanh(g)
            float tc = 2.f * __builtin_amdgcn_rcpf(1.f + __expf(-2.f * cval)) - 1.f;
            float hn = so * tc;                          // h = o*tanh(c')
            hval = hn;

            if (lane < HID) *outp = hn;                  // fire-and-forget
            outp += ts * 60;
        }
        if (w + 1 < NW) stage_write((w + 1) & 1);
    }
}

__global__ void fc_kernel(const float* __restrict__ hbuf,  // [B, T, 60]
                          const float* __restrict__ fc_w,  // [2, 60]
                          const float* __restrict__ fc_b,  // [2]
                          float* __restrict__ out)         // [B, 2]
{
    int b = threadIdx.x;
    if (b < BATCH) {
        const float* h = hbuf + ((size_t)b * T_LEN + (T_LEN - 1)) * 60;
        #pragma unroll
        for (int j = 0; j < 2; j++) {
            float acc = fc_b[j];
            #pragma unroll
            for (int k = 0; k < 60; k++) acc += fc_w[j * 60 + k] * h[k];
            out[b * 2 + j] = ftanh(acc);
        }
    }
}

extern "C" void kernel_launch(void* const* d_in, const int* in_sizes, int n_in,
                              void* d_out, int out_size, void* d_ws, size_t ws_size,
                              hipStream_t stream) {
    const float* x          = (const float*)d_in[0];
    const float* w_ih1_l0   = (const float*)d_in[1];
    const float* w_ih1_rest = (const float*)d_in[2];
    const float* w_hh1      = (const float*)d_in[3];
    const float* b1         = (const float*)d_in[4];
    const float* w_ih2      = (const float*)d_in[5];
    const float* w_hh2      = (const float*)d_in[6];
    const float* b2         = (const float*)d_in[7];
    const float* h01        = (const float*)d_in[8];
    const float* c01        = (const float*)d_in[9];
    const float* h02        = (const float*)d_in[10];
    const float* c02        = (const float*)d_in[11];
    const float* fc_w       = (const float*)d_in[12];
    const float* fc_b       = (const float*)d_in[13];
    float* out = (float*)d_out;

    float* bufA = (float*)d_ws;
    float* bufB = bufA + (size_t)BATCH * T_LEN * 60;

    dim3 grid(BATCH, 2), blk(64);

    // ---- stack 1 ----
    lstm_wave<21><<<grid, blk, 0, stream>>>(x, bufA,
        w_ih1_l0, w_hh1, b1, h01, c01);
    const float* curb = bufA;
    float*       nxtb = bufB;
    for (int l = 1; l < 5; l++) {
        lstm_wave<60><<<grid, blk, 0, stream>>>(curb, nxtb,
            w_ih1_rest + (size_t)(l - 1) * 2 * 120 * 60,
            w_hh1      + (size_t)l * 2 * 120 * HID,
            b1         + (size_t)l * 2 * 120,
            h01        + (size_t)l * 2 * BATCH * HID,
            c01        + (size_t)l * 2 * BATCH * HID);
        float* tmp = (float*)curb; curb = nxtb; nxtb = tmp;
    }
    // ---- stack 2 ----
    for (int l = 0; l < 5; l++) {
        lstm_wave<60><<<grid, blk, 0, stream>>>(curb, nxtb,
            w_ih2 + (size_t)l * 2 * 120 * 60,
            w_hh2 + (size_t)l * 2 * 120 * HID,
            b2    + (size_t)l * 2 * 120,
            h02   + (size_t)l * 2 * BATCH * HID,
            c02   + (size_t)l * 2 * BATCH * HID);
        float* tmp = (float*)curb; curb = nxtb; nxtb = tmp;
    }

    fc_kernel<<<1, 256, 0, stream>>>(curb, fc_w, fc_b, out);
}